// Round 1
// baseline (918.329 us; speedup 1.0000x reference)
//
#include <hip/hip_runtime.h>
#include <math.h>

#define DIM 512
#define SEQ 8192
#define BATCH 4
#define RTOT (BATCH*SEQ)   // 32768 rows
#define SCALE 0.125f       // 1/sqrt(64)

// ws layout in floats
#define OFF_KV 0           // 4*4*64 = 1024
#define OFF_KS 1024        // 1024
#define OFF_R  2048        // 32768 per-row rsqrt factors

__device__ __forceinline__ float phi_f(float x){
    // max(elu(x), -0.99) + 1  ==  x>0 ? x+1 : max(exp(x), 0.01)
    return x > 0.f ? x + 1.f : fmaxf(expf(x), 0.01f);
}

// ---------------- K0: per-row rms factor + zero accumulators ----------------
__global__ __launch_bounds__(256) void k_rms(const float* __restrict__ x, float* __restrict__ ws){
    const int row  = blockIdx.x*4 + (threadIdx.x>>6);
    const int lane = threadIdx.x & 63;
    const float4* xr = (const float4*)(x + (size_t)row*DIM);
    float4 a = xr[lane];
    float4 b = xr[lane+64];
    float s = a.x*a.x+a.y*a.y+a.z*a.z+a.w*a.w
            + b.x*b.x+b.y*b.y+b.z*b.z+b.w*b.w;
    #pragma unroll
    for(int off=32; off; off>>=1) s += __shfl_xor(s, off, 64);
    if(lane==0) ws[OFF_R+row] = rsqrtf(s*(1.0f/DIM) + 1e-6f);
    if(blockIdx.x==0){
        for(int i=threadIdx.x;i<2048;i+=256) ws[i]=0.f;
    }
}

// ---------------- K1: k/v projection + KV / K_sum reduction ----------------
// block = 256 threads; tile 128 rows x (64 k-cols + 64 v-cols) for kv head blockIdx.y
__global__ __launch_bounds__(256) void k_kv(const float* __restrict__ x, const float* __restrict__ g,
                                            const float* __restrict__ wk, const float* __restrict__ wv,
                                            float* __restrict__ ws){
    __shared__ float sAT[16][128];   // [kk][row], h = x*r*g staged transposed
    __shared__ float sB[16][128];    // [kk][j]: j<64 -> wk row, j>=64 -> wv row
    __shared__ float rl[128];
    __shared__ float red[64][16];

    const int t  = threadIdx.x;
    const int r0 = blockIdx.x * 128;
    const int gh = blockIdx.y;          // kv head
    const int b  = r0 / SEQ;

    if(t < 128) rl[t] = ws[OFF_R + r0 + t];

    const int ti = t & 15, tj = t >> 4;
    const int ri = ti*4;                // rows ri..ri+3 and ri+64..ri+67
    const int cj = tj*4;                // k cols cj..cj+3 (d index), v cols 64+cj..

    const int srow = t & 127;
    const int skk  = (t >> 7) * 8;      // 0 or 8
    const float* xrow = x + (size_t)(r0 + srow)*DIM + skk;
    const float* wrow = (srow < 64) ? (wk + (size_t)(gh*64 + srow)*DIM + skk)
                                    : (wv + (size_t)(gh*64 + (srow-64))*DIM + skk);
    const float* gp = g + skk;

    float accK[8][4], accV[8][4];
    #pragma unroll
    for(int i=0;i<8;i++)
        #pragma unroll
        for(int j=0;j<4;j++){ accK[i][j]=0.f; accV[i][j]=0.f; }

    __syncthreads();
    const float rr = rl[srow];

    for(int k0=0;k0<DIM;k0+=16){
        float4 xa = *(const float4*)(xrow + k0);
        float4 xb = *(const float4*)(xrow + k0 + 4);
        float4 ga = *(const float4*)(gp + k0);
        float4 gb = *(const float4*)(gp + k0 + 4);
        float4 wa = *(const float4*)(wrow + k0);
        float4 wb = *(const float4*)(wrow + k0 + 4);
        __syncthreads();   // previous tile's compute done
        sAT[skk+0][srow]=xa.x*ga.x*rr;
        sAT[skk+1][srow]=xa.y*ga.y*rr;
        sAT[skk+2][srow]=xa.z*ga.z*rr;
        sAT[skk+3][srow]=xa.w*ga.w*rr;
        sAT[skk+4][srow]=xb.x*gb.x*rr;
        sAT[skk+5][srow]=xb.y*gb.y*rr;
        sAT[skk+6][srow]=xb.z*gb.z*rr;
        sAT[skk+7][srow]=xb.w*gb.w*rr;
        sB[skk+0][srow]=wa.x;
        sB[skk+1][srow]=wa.y;
        sB[skk+2][srow]=wa.z;
        sB[skk+3][srow]=wa.w;
        sB[skk+4][srow]=wb.x;
        sB[skk+5][srow]=wb.y;
        sB[skk+6][srow]=wb.z;
        sB[skk+7][srow]=wb.w;
        __syncthreads();
        #pragma unroll
        for(int kk=0;kk<16;kk++){
            float4 a0 = *(const float4*)&sAT[kk][ri];
            float4 a1 = *(const float4*)&sAT[kk][ri+64];
            float4 bk = *(const float4*)&sB[kk][cj];
            float4 bv = *(const float4*)&sB[kk][cj+64];
            float av[8] = {a0.x,a0.y,a0.z,a0.w,a1.x,a1.y,a1.z,a1.w};
            float bk4[4]= {bk.x,bk.y,bk.z,bk.w};
            float bv4[4]= {bv.x,bv.y,bv.z,bv.w};
            #pragma unroll
            for(int i=0;i<8;i++)
                #pragma unroll
                for(int j=0;j<4;j++){
                    accK[i][j] = fmaf(av[i], bk4[j], accK[i][j]);
                    accV[i][j] = fmaf(av[i], bv4[j], accV[i][j]);
                }
        }
    }

    // epilogue: K = phi(acc*SCALE); partial sums over this thread's 8 rows
    float pKV[4], pKs[4];
    #pragma unroll
    for(int j=0;j<4;j++){
        float skv=0.f, sks=0.f;
        #pragma unroll
        for(int i=0;i<8;i++){
            float kvv = phi_f(accK[i][j]*SCALE);
            skv = fmaf(kvv, accV[i][j], skv);
            sks += kvv;
        }
        pKV[j]=skv; pKs[j]=sks;
    }
    __syncthreads();
    #pragma unroll
    for(int j=0;j<4;j++) red[cj+j][ti] = pKV[j];
    __syncthreads();
    if(t<64){
        float s2=0.f;
        for(int i=0;i<16;i++) s2 += red[t][i];
        atomicAdd(&ws[OFF_KV + b*256 + gh*64 + t], s2);
    }
    __syncthreads();
    #pragma unroll
    for(int j=0;j<4;j++) red[cj+j][ti] = pKs[j];
    __syncthreads();
    if(t<64){
        float s2=0.f;
        for(int i=0;i<16;i++) s2 += red[t][i];
        atomicAdd(&ws[OFF_KS + b*256 + gh*64 + t], s2);
    }
}

// ---------------- K2: q proj -> phi -> Z -> Y -> out GEMM (fused) ----------------
// block = 256 threads, 32 rows per block. Q/Y kept transposed in LDS: qT[col][row]
__global__ __launch_bounds__(256) void k_qo(const float* __restrict__ x, const float* __restrict__ g,
                                            const float* __restrict__ wq, const float* __restrict__ wo,
                                            const float* __restrict__ ws, float* __restrict__ out){
    __shared__ float qT[512][32];    // 64 KB
    __shared__ float sAT[16][32];    // staged h (transposed)
    __shared__ float sB[16][128];    // weight tile [kk][j]
    __shared__ float rl[32];
    __shared__ float KVl[256];
    __shared__ float Ksl[256];
    __shared__ float zb[256];        // 1/(Z+1e-6) per (row,head)

    const int t  = threadIdx.x;
    const int r0 = blockIdx.x * 32;
    const int b  = r0 / SEQ;

    if(t<32) rl[t] = ws[OFF_R + r0 + t];
    KVl[t] = ws[OFF_KV + b*256 + t];
    Ksl[t] = ws[OFF_KS + b*256 + t];

    const int ti = t & 7, tj = t >> 3;
    const int ri = ti*4, cj = tj*4;       // tile 32 rows x 128 cols, 4x4 per thread
    const int srow = t & 31, skk = (t>>5)*2;
    const int sj = t & 127, skkB = (t>>7)*8;
    const float* xrow = x + (size_t)(r0+srow)*DIM + skk;
    const float* gp = g + skk;

    __syncthreads();
    const float rr = rl[srow];

    // ---- Phase B: q GEMM, 4 col-tiles of 128 ----
    for(int ct=0; ct<4; ct++){
        const float* wqb = wq + (size_t)(ct*128 + sj)*DIM + skkB;
        float acc[4][4];
        #pragma unroll
        for(int i=0;i<4;i++)
            #pragma unroll
            for(int j=0;j<4;j++) acc[i][j]=0.f;
        for(int k0=0;k0<DIM;k0+=16){
            float2 xa = *(const float2*)(xrow + k0);
            float2 ga = *(const float2*)(gp + k0);
            float4 wa = *(const float4*)(wqb + k0);
            float4 wb2= *(const float4*)(wqb + k0 + 4);
            __syncthreads();
            sAT[skk+0][srow] = xa.x*ga.x*rr;
            sAT[skk+1][srow] = xa.y*ga.y*rr;
            sB[skkB+0][sj]=wa.x;
            sB[skkB+1][sj]=wa.y;
            sB[skkB+2][sj]=wa.z;
            sB[skkB+3][sj]=wa.w;
            sB[skkB+4][sj]=wb2.x;
            sB[skkB+5][sj]=wb2.y;
            sB[skkB+6][sj]=wb2.z;
            sB[skkB+7][sj]=wb2.w;
            __syncthreads();
            #pragma unroll
            for(int kk=0;kk<16;kk++){
                float4 a = *(const float4*)&sAT[kk][ri];
                float4 bb= *(const float4*)&sB[kk][cj];
                float av[4]={a.x,a.y,a.z,a.w};
                float bv[4]={bb.x,bb.y,bb.z,bb.w};
                #pragma unroll
                for(int i=0;i<4;i++)
                    #pragma unroll
                    for(int j=0;j<4;j++)
                        acc[i][j] = fmaf(av[i], bv[j], acc[i][j]);
            }
        }
        #pragma unroll
        for(int i=0;i<4;i++)
            #pragma unroll
            for(int j=0;j<4;j++)
                qT[ct*128+cj+j][ri+i] = phi_f(acc[i][j]*SCALE);
    }
    __syncthreads();

    // ---- Phase C: Z per (row, head), store reciprocal ----
    {
        const int row = t>>3, h = t&7;
        const float* ks = &Ksl[(h>>1)*64];
        float z = 0.f;
        #pragma unroll
        for(int d=0;d<64;d++) z = fmaf(qT[h*64+d][row], ks[d], z);
        zb[row*8+h] = 1.0f/(z + 1e-6f);
    }
    __syncthreads();

    // ---- Phase D: Y = Q * KV_rep * (1/(Z+eps)) in place ----
    #pragma unroll 4
    for(int i2=0;i2<64;i2++){
        int f = i2*256 + t;
        int col = f>>5, row = f&31;
        int h = col>>6;
        float kvv = KVl[((h>>1)<<6) + (col&63)];
        qT[col][row] *= kvv * zb[row*8+h];
    }
    __syncthreads();

    // ---- Phase E: out = Y @ wo^T, A read directly from qT ----
    for(int ct=0;ct<4;ct++){
        const float* wob = wo + (size_t)(ct*128 + sj)*DIM + skkB;
        float acc[4][4];
        #pragma unroll
        for(int i=0;i<4;i++)
            #pragma unroll
            for(int j=0;j<4;j++) acc[i][j]=0.f;
        for(int k0=0;k0<DIM;k0+=16){
            float4 wa = *(const float4*)(wob + k0);
            float4 wb2= *(const float4*)(wob + k0 + 4);
            __syncthreads();
            sB[skkB+0][sj]=wa.x;
            sB[skkB+1][sj]=wa.y;
            sB[skkB+2][sj]=wa.z;
            sB[skkB+3][sj]=wa.w;
            sB[skkB+4][sj]=wb2.x;
            sB[skkB+5][sj]=wb2.y;
            sB[skkB+6][sj]=wb2.z;
            sB[skkB+7][sj]=wb2.w;
            __syncthreads();
            #pragma unroll
            for(int kk=0;kk<16;kk++){
                float4 a = *(const float4*)&qT[k0+kk][ri];
                float4 bb= *(const float4*)&sB[kk][cj];
                float av[4]={a.x,a.y,a.z,a.w};
                float bv[4]={bb.x,bb.y,bb.z,bb.w};
                #pragma unroll
                for(int i=0;i<4;i++)
                    #pragma unroll
                    for(int j=0;j<4;j++)
                        acc[i][j] = fmaf(av[i], bv[j], acc[i][j]);
            }
        }
        #pragma unroll
        for(int i=0;i<4;i++){
            float4 st; st.x=acc[i][0]; st.y=acc[i][1]; st.z=acc[i][2]; st.w=acc[i][3];
            *(float4*)(out + (size_t)(r0+ri+i)*DIM + ct*128 + cj) = st;
        }
    }
}

extern "C" void kernel_launch(void* const* d_in, const int* in_sizes, int n_in,
                              void* d_out, int out_size, void* d_ws, size_t ws_size,
                              hipStream_t stream){
    (void)in_sizes; (void)n_in; (void)out_size; (void)ws_size;
    const float* x  = (const float*)d_in[0];
    const float* g  = (const float*)d_in[1];
    const float* wq = (const float*)d_in[2];
    const float* wk = (const float*)d_in[3];
    const float* wv = (const float*)d_in[4];
    const float* wo = (const float*)d_in[5];
    float* out = (float*)d_out;
    float* ws  = (float*)d_ws;

    hipLaunchKernelGGL(k_rms, dim3(RTOT/4), dim3(256), 0, stream, x, ws);
    hipLaunchKernelGGL(k_kv,  dim3(RTOT/128, 4), dim3(256), 0, stream, x, g, wk, wv, ws);
    hipLaunchKernelGGL(k_qo,  dim3(RTOT/32), dim3(256), 0, stream, x, g, wq, wo, ws, out);
}

// Round 2
// 228.691 us; speedup vs baseline: 4.0156x; 4.0156x over previous
//
#include <hip/hip_runtime.h>
#include <math.h>

#define DIM 512
#define SEQ 8192
#define BATCH 4
#define RTOT (BATCH*SEQ)   // 32768 rows
#define SCALE 0.125f       // 1/sqrt(64)

typedef unsigned short ushort_t;
typedef __attribute__((ext_vector_type(8))) short short8;
typedef __attribute__((ext_vector_type(4))) float float4v;

#define AS1(p) ((__attribute__((address_space(1))) void*)(p))
#define AS3(p) ((__attribute__((address_space(3))) void*)(p))

__device__ __forceinline__ float phi_f(float x){
    // max(elu(x), -0.99) + 1  ==  x>0 ? x+1 : max(exp(x), 0.01)
    return x > 0.f ? x + 1.f : fmaxf(expf(x), 0.01f);
}

__device__ __forceinline__ unsigned short f2bf(float f){
    unsigned int u = __float_as_uint(f);
    u += 0x7fffu + ((u >> 16) & 1u);   // round-to-nearest-even
    return (unsigned short)(u >> 16);
}

// ================= FAST PATH (bf16 MFMA) =================
// ws byte layout:
//   [0, 4096)          KV  float[1024]  (b*256 + gh*64 + d)
//   [4096, 8192)       Ks  float[1024]
//   [8192, +512K)      wqb  ushort[512*512]
//   ... wob  ushort[512*512]
//   ... wkvb ushort[4*128*512]   (per kv head: 64 wk rows then 64 wv rows)
//   ... hb   ushort[32768*512]
//   ... yb   ushort[32768*512]
#define WS_NEED 68689920ull

// ---------- K0: rmsnorm factor + h = x*g*r cast to bf16 ----------
__global__ __launch_bounds__(256) void k_rmsh(const float* __restrict__ x, const float* __restrict__ g,
                                              float* __restrict__ wsf, ushort_t* __restrict__ hb){
    const int t = threadIdx.x, w = t>>6, L = t&63;
    const int row = blockIdx.x*4 + w;
    const float4* xr = (const float4*)(x + (size_t)row*DIM);
    float4 a = xr[L*2], c = xr[L*2+1];
    float s = a.x*a.x+a.y*a.y+a.z*a.z+a.w*a.w
            + c.x*c.x+c.y*c.y+c.z*c.z+c.w*c.w;
    #pragma unroll
    for(int off=1; off<64; off<<=1) s += __shfl_xor(s, off, 64);
    const float rf = rsqrtf(s*(1.0f/DIM) + 1e-6f);
    const float4* gr = (const float4*)g;
    float4 ga = gr[L*2], gb = gr[L*2+1];
    uint4 p;
    p.x = (unsigned)f2bf(a.x*ga.x*rf) | ((unsigned)f2bf(a.y*ga.y*rf)<<16);
    p.y = (unsigned)f2bf(a.z*ga.z*rf) | ((unsigned)f2bf(a.w*ga.w*rf)<<16);
    p.z = (unsigned)f2bf(c.x*gb.x*rf) | ((unsigned)f2bf(c.y*gb.y*rf)<<16);
    p.w = (unsigned)f2bf(c.z*gb.z*rf) | ((unsigned)f2bf(c.w*gb.w*rf)<<16);
    *(uint4*)(hb + (size_t)row*DIM + L*8) = p;
    if(blockIdx.x==0){
        for(int i=t;i<2048;i+=256) wsf[i]=0.f;
    }
}

// ---------- K0b: cast weights to bf16 (wq, wo verbatim; wk+wv interleaved per head) ----------
__global__ __launch_bounds__(256) void k_wcast(const float* __restrict__ wq, const float* __restrict__ wk,
                                               const float* __restrict__ wv, const float* __restrict__ wo,
                                               ushort_t* __restrict__ wqb, ushort_t* __restrict__ wob,
                                               ushort_t* __restrict__ wkvb){
    const int idx = (blockIdx.x*256 + threadIdx.x)*4;
    const float* src; ushort_t* dst; int di;
    if(idx < 262144){ src = wq + idx; dst = wqb; di = idx; }
    else if(idx < 524288){ di = idx - 262144; src = wo + di; dst = wob; }
    else {
        int f = idx - 524288;
        int g = f >> 16, rem = f & 65535;
        int row = rem >> 9, col = rem & 511;
        src = (row < 64) ? (wk + (size_t)((g<<6)+row)*DIM + col)
                         : (wv + (size_t)((g<<6)+row-64)*DIM + col);
        dst = wkvb; di = f;
    }
    float4 v = *(const float4*)src;
    uint2 p;
    p.x = (unsigned)f2bf(v.x) | ((unsigned)f2bf(v.y)<<16);
    p.y = (unsigned)f2bf(v.z) | ((unsigned)f2bf(v.w)<<16);
    *(uint2*)(dst + di) = p;
}

// ---------- K1: k/v GEMM (bf16 MFMA) + phi + KV/K_sum reduction ----------
// grid (RTOT/128, 4). Tile 128 rows x 128 cols (64 k-cols + 64 v-cols of head gh).
// Wave w: rows w*32..w*32+31 (2 m-tiles), all 8 n-tiles -> K/V pairing in-register.
__global__ __launch_bounds__(256) void k_kv_mfma(const ushort_t* __restrict__ hb,
                                                 const ushort_t* __restrict__ wkvb,
                                                 float* __restrict__ wsf){
    __shared__ ushort_t At[128*32];
    __shared__ ushort_t Bt[128*32];
    const int t = threadIdx.x, w = t>>6, L = t&63;
    const int lr = L&15, q = L>>4;
    const int r0 = blockIdx.x*128, gh = blockIdx.y;
    const int b = r0 >> 13;
    const int c0 = t, c1 = 256+t;
    const ushort_t* gA0 = hb + (size_t)(r0 + (c0>>2))*DIM + (c0&3)*8;
    const ushort_t* gA1 = hb + (size_t)(r0 + (c1>>2))*DIM + (c1&3)*8;
    const ushort_t* wb  = wkvb + (size_t)gh*128*DIM;
    const ushort_t* gB0 = wb + (size_t)(c0>>2)*DIM + (c0&3)*8;
    const ushort_t* gB1 = wb + (size_t)(c1>>2)*DIM + (c1&3)*8;

    float4v acc[2][8];
    #pragma unroll
    for(int i=0;i<2;i++)
        #pragma unroll
        for(int j=0;j<8;j++) acc[i][j] = (float4v){0.f,0.f,0.f,0.f};

    for(int ks=0; ks<16; ks++){
        __syncthreads();
        __builtin_amdgcn_global_load_lds(AS1(gA0), AS3(At + (w*64)*8),       16, 0, 0);
        __builtin_amdgcn_global_load_lds(AS1(gA1), AS3(At + (256 + w*64)*8), 16, 0, 0);
        __builtin_amdgcn_global_load_lds(AS1(gB0), AS3(Bt + (w*64)*8),       16, 0, 0);
        __builtin_amdgcn_global_load_lds(AS1(gB1), AS3(Bt + (256 + w*64)*8), 16, 0, 0);
        gA0 += 32; gA1 += 32; gB0 += 32; gB1 += 32;
        __syncthreads();
        short8 af[2], bf[8];
        #pragma unroll
        for(int mt=0; mt<2; mt++)
            af[mt] = *(const short8*)(At + (w*32 + mt*16 + lr)*32 + q*8);
        #pragma unroll
        for(int nt=0; nt<8; nt++)
            bf[nt] = *(const short8*)(Bt + (nt*16 + lr)*32 + q*8);
        #pragma unroll
        for(int mt=0; mt<2; mt++)
            #pragma unroll
            for(int nt=0; nt<8; nt++)
                acc[mt][nt] = __builtin_amdgcn_mfma_f32_16x16x32_bf16(af[mt], bf[nt], acc[mt][nt], 0,0,0);
    }

    // epilogue: K = phi(accK*SCALE); KV += K*V; Ks += K  (per d = nt*16+lr)
    #pragma unroll
    for(int nt=0; nt<4; nt++){
        float skv=0.f, sks=0.f;
        #pragma unroll
        for(int mt=0; mt<2; mt++)
            #pragma unroll
            for(int r=0; r<4; r++){
                float K = phi_f(acc[mt][nt][r]*SCALE);
                skv = fmaf(K, acc[mt][nt+4][r], skv);
                sks += K;
            }
        skv += __shfl_xor(skv,16,64); skv += __shfl_xor(skv,32,64);
        sks += __shfl_xor(sks,16,64); sks += __shfl_xor(sks,32,64);
        if(q==0){
            atomicAdd(&wsf[       b*256 + gh*64 + nt*16 + lr], skv);
            atomicAdd(&wsf[1024 + b*256 + gh*64 + nt*16 + lr], sks);
        }
    }
}

// ---------- K2: q GEMM (bf16 MFMA) + phi + Z + Y -> yb (bf16) ----------
// grid (RTOT/128, 4): ct = column tile = heads {2ct, 2ct+1}, kv-head ct.
__global__ __launch_bounds__(256) void k_q_mfma(const ushort_t* __restrict__ hb,
                                                const ushort_t* __restrict__ wqb,
                                                const float* __restrict__ wsf,
                                                ushort_t* __restrict__ yb){
    __shared__ ushort_t At[128*32];
    __shared__ ushort_t Bt[128*32];
    __shared__ ushort_t Yt[128*128];
    const int t = threadIdx.x, w = t>>6, L = t&63;
    const int lr = L&15, q = L>>4;
    const int wr = w>>1, wc = w&1;
    const int r0 = blockIdx.x*128, ct = blockIdx.y;
    const int b = r0 >> 13;
    const int c0 = t, c1 = 256+t;
    const ushort_t* gA0 = hb + (size_t)(r0 + (c0>>2))*DIM + (c0&3)*8;
    const ushort_t* gA1 = hb + (size_t)(r0 + (c1>>2))*DIM + (c1&3)*8;
    const ushort_t* wbq = wqb + (size_t)ct*128*DIM;
    const ushort_t* gB0 = wbq + (size_t)(c0>>2)*DIM + (c0&3)*8;
    const ushort_t* gB1 = wbq + (size_t)(c1>>2)*DIM + (c1&3)*8;

    float4v acc[4][4];
    #pragma unroll
    for(int i=0;i<4;i++)
        #pragma unroll
        for(int j=0;j<4;j++) acc[i][j] = (float4v){0.f,0.f,0.f,0.f};

    for(int ks=0; ks<16; ks++){
        __syncthreads();
        __builtin_amdgcn_global_load_lds(AS1(gA0), AS3(At + (w*64)*8),       16, 0, 0);
        __builtin_amdgcn_global_load_lds(AS1(gA1), AS3(At + (256 + w*64)*8), 16, 0, 0);
        __builtin_amdgcn_global_load_lds(AS1(gB0), AS3(Bt + (w*64)*8),       16, 0, 0);
        __builtin_amdgcn_global_load_lds(AS1(gB1), AS3(Bt + (256 + w*64)*8), 16, 0, 0);
        gA0 += 32; gA1 += 32; gB0 += 32; gB1 += 32;
        __syncthreads();
        short8 af[4], bf[4];
        #pragma unroll
        for(int mt=0; mt<4; mt++)
            af[mt] = *(const short8*)(At + (wr*64 + mt*16 + lr)*32 + q*8);
        #pragma unroll
        for(int nt=0; nt<4; nt++)
            bf[nt] = *(const short8*)(Bt + (wc*64 + nt*16 + lr)*32 + q*8);
        #pragma unroll
        for(int mt=0; mt<4; mt++)
            #pragma unroll
            for(int nt=0; nt<4; nt++)
                acc[mt][nt] = __builtin_amdgcn_mfma_f32_16x16x32_bf16(af[mt], bf[nt], acc[mt][nt], 0,0,0);
    }

    // epilogue: Q=phi(acc*SCALE); Z=Q.Ksum per row; Y=Q*KV/(Z+eps) -> bf16
    float ksf[4], kvf[4];
    #pragma unroll
    for(int nt=0; nt<4; nt++){
        ksf[nt] = wsf[1024 + b*256 + ct*64 + nt*16 + lr];
        kvf[nt] = wsf[       b*256 + ct*64 + nt*16 + lr];
    }
    #pragma unroll
    for(int mt=0; mt<4; mt++)
        #pragma unroll
        for(int nt=0; nt<4; nt++)
            #pragma unroll
            for(int r=0; r<4; r++)
                acc[mt][nt][r] = phi_f(acc[mt][nt][r]*SCALE);
    float zi[4][4];
    #pragma unroll
    for(int mt=0; mt<4; mt++)
        #pragma unroll
        for(int r=0; r<4; r++){
            float zv = acc[mt][0][r]*ksf[0] + acc[mt][1][r]*ksf[1]
                     + acc[mt][2][r]*ksf[2] + acc[mt][3][r]*ksf[3];
            zv += __shfl_xor(zv,1,64); zv += __shfl_xor(zv,2,64);
            zv += __shfl_xor(zv,4,64); zv += __shfl_xor(zv,8,64);
            zi[mt][r] = 1.0f/(zv + 1e-6f);
        }
    #pragma unroll
    for(int mt=0; mt<4; mt++)
        #pragma unroll
        for(int nt=0; nt<4; nt++)
            #pragma unroll
            for(int r=0; r<4; r++)
                Yt[(wr*64 + mt*16 + q*4 + r)*128 + wc*64 + nt*16 + lr]
                    = f2bf(acc[mt][nt][r]*kvf[nt]*zi[mt][r]);
    __syncthreads();
    #pragma unroll
    for(int i=0;i<8;i++){
        int u = (i*256 + t)*8;
        int rr = u>>7, cc = u&127;
        *(uint4*)(yb + (size_t)(r0+rr)*DIM + ct*128 + cc) = *(const uint4*)(Yt + u);
    }
}

// ---------- K3: out = Y @ wo^T (bf16 MFMA), fp32 store ----------
__global__ __launch_bounds__(256) void k_out_mfma(const ushort_t* __restrict__ yb,
                                                  const ushort_t* __restrict__ wob,
                                                  float* __restrict__ out){
    __shared__ ushort_t At[128*32];
    __shared__ ushort_t Bt[128*32];
    const int t = threadIdx.x, w = t>>6, L = t&63;
    const int lr = L&15, q = L>>4;
    const int wr = w>>1, wc = w&1;
    const int r0 = blockIdx.x*128, ct = blockIdx.y;
    const int c0 = t, c1 = 256+t;
    const ushort_t* gA0 = yb + (size_t)(r0 + (c0>>2))*DIM + (c0&3)*8;
    const ushort_t* gA1 = yb + (size_t)(r0 + (c1>>2))*DIM + (c1&3)*8;
    const ushort_t* wbo = wob + (size_t)ct*128*DIM;
    const ushort_t* gB0 = wbo + (size_t)(c0>>2)*DIM + (c0&3)*8;
    const ushort_t* gB1 = wbo + (size_t)(c1>>2)*DIM + (c1&3)*8;

    float4v acc[4][4];
    #pragma unroll
    for(int i=0;i<4;i++)
        #pragma unroll
        for(int j=0;j<4;j++) acc[i][j] = (float4v){0.f,0.f,0.f,0.f};

    for(int ks=0; ks<16; ks++){
        __syncthreads();
        __builtin_amdgcn_global_load_lds(AS1(gA0), AS3(At + (w*64)*8),       16, 0, 0);
        __builtin_amdgcn_global_load_lds(AS1(gA1), AS3(At + (256 + w*64)*8), 16, 0, 0);
        __builtin_amdgcn_global_load_lds(AS1(gB0), AS3(Bt + (w*64)*8),       16, 0, 0);
        __builtin_amdgcn_global_load_lds(AS1(gB1), AS3(Bt + (256 + w*64)*8), 16, 0, 0);
        gA0 += 32; gA1 += 32; gB0 += 32; gB1 += 32;
        __syncthreads();
        short8 af[4], bf[4];
        #pragma unroll
        for(int mt=0; mt<4; mt++)
            af[mt] = *(const short8*)(At + (wr*64 + mt*16 + lr)*32 + q*8);
        #pragma unroll
        for(int nt=0; nt<4; nt++)
            bf[nt] = *(const short8*)(Bt + (wc*64 + nt*16 + lr)*32 + q*8);
        #pragma unroll
        for(int mt=0; mt<4; mt++)
            #pragma unroll
            for(int nt=0; nt<4; nt++)
                acc[mt][nt] = __builtin_amdgcn_mfma_f32_16x16x32_bf16(af[mt], bf[nt], acc[mt][nt], 0,0,0);
    }
    #pragma unroll
    for(int mt=0; mt<4; mt++)
        #pragma unroll
        for(int nt=0; nt<4; nt++)
            #pragma unroll
            for(int r=0; r<4; r++)
                out[(size_t)(r0 + wr*64 + mt*16 + q*4 + r)*DIM + ct*128 + wc*64 + nt*16 + lr]
                    = acc[mt][nt][r];
}

// ================= FALLBACK PATH (fp32 vector, R1 — used only if ws too small) =================
#define OFF_KV 0
#define OFF_KS 1024
#define OFF_R  2048

__global__ __launch_bounds__(256) void k_rms_f32(const float* __restrict__ x, float* __restrict__ ws){
    const int row  = blockIdx.x*4 + (threadIdx.x>>6);
    const int lane = threadIdx.x & 63;
    const float4* xr = (const float4*)(x + (size_t)row*DIM);
    float4 a = xr[lane];
    float4 b = xr[lane+64];
    float s = a.x*a.x+a.y*a.y+a.z*a.z+a.w*a.w
            + b.x*b.x+b.y*b.y+b.z*b.z+b.w*b.w;
    #pragma unroll
    for(int off=32; off; off>>=1) s += __shfl_xor(s, off, 64);
    if(lane==0) ws[OFF_R+row] = rsqrtf(s*(1.0f/DIM) + 1e-6f);
    if(blockIdx.x==0){
        for(int i=threadIdx.x;i<2048;i+=256) ws[i]=0.f;
    }
}

__global__ __launch_bounds__(256) void k_kv_f32(const float* __restrict__ x, const float* __restrict__ g,
                                            const float* __restrict__ wk, const float* __restrict__ wv,
                                            float* __restrict__ ws){
    __shared__ float sAT[16][128];
    __shared__ float sB[16][128];
    __shared__ float rl[128];
    __shared__ float red[64][16];
    const int t  = threadIdx.x;
    const int r0 = blockIdx.x * 128;
    const int gh = blockIdx.y;
    const int b  = r0 / SEQ;
    if(t < 128) rl[t] = ws[OFF_R + r0 + t];
    const int ti = t & 15, tj = t >> 4;
    const int ri = ti*4, cj = tj*4;
    const int srow = t & 127;
    const int skk  = (t >> 7) * 8;
    const float* xrow = x + (size_t)(r0 + srow)*DIM + skk;
    const float* wrow = (srow < 64) ? (wk + (size_t)(gh*64 + srow)*DIM + skk)
                                    : (wv + (size_t)(gh*64 + (srow-64))*DIM + skk);
    const float* gp = g + skk;
    float accK[8][4], accV[8][4];
    #pragma unroll
    for(int i=0;i<8;i++)
        #pragma unroll
        for(int j=0;j<4;j++){ accK[i][j]=0.f; accV[i][j]=0.f; }
    __syncthreads();
    const float rr = rl[srow];
    for(int k0=0;k0<DIM;k0+=16){
        float4 xa = *(const float4*)(xrow + k0);
        float4 xb = *(const float4*)(xrow + k0 + 4);
        float4 ga = *(const float4*)(gp + k0);
        float4 gb = *(const float4*)(gp + k0 + 4);
        float4 wa = *(const float4*)(wrow + k0);
        float4 wb = *(const float4*)(wrow + k0 + 4);
        __syncthreads();
        sAT[skk+0][srow]=xa.x*ga.x*rr; sAT[skk+1][srow]=xa.y*ga.y*rr;
        sAT[skk+2][srow]=xa.z*ga.z*rr; sAT[skk+3][srow]=xa.w*ga.w*rr;
        sAT[skk+4][srow]=xb.x*gb.x*rr; sAT[skk+5][srow]=xb.y*gb.y*rr;
        sAT[skk+6][srow]=xb.z*gb.z*rr; sAT[skk+7][srow]=xb.w*gb.w*rr;
        sB[skk+0][srow]=wa.x; sB[skk+1][srow]=wa.y; sB[skk+2][srow]=wa.z; sB[skk+3][srow]=wa.w;
        sB[skk+4][srow]=wb.x; sB[skk+5][srow]=wb.y; sB[skk+6][srow]=wb.z; sB[skk+7][srow]=wb.w;
        __syncthreads();
        #pragma unroll
        for(int kk=0;kk<16;kk++){
            float4 a0 = *(const float4*)&sAT[kk][ri];
            float4 a1 = *(const float4*)&sAT[kk][ri+64];
            float4 bk = *(const float4*)&sB[kk][cj];
            float4 bv = *(const float4*)&sB[kk][cj+64];
            float av[8] = {a0.x,a0.y,a0.z,a0.w,a1.x,a1.y,a1.z,a1.w};
            float bk4[4]= {bk.x,bk.y,bk.z,bk.w};
            float bv4[4]= {bv.x,bv.y,bv.z,bv.w};
            #pragma unroll
            for(int i=0;i<8;i++)
                #pragma unroll
                for(int j=0;j<4;j++){
                    accK[i][j] = fmaf(av[i], bk4[j], accK[i][j]);
                    accV[i][j] = fmaf(av[i], bv4[j], accV[i][j]);
                }
        }
    }
    float pKV[4], pKs[4];
    #pragma unroll
    for(int j=0;j<4;j++){
        float skv=0.f, sks=0.f;
        #pragma unroll
        for(int i=0;i<8;i++){
            float kvv = phi_f(accK[i][j]*SCALE);
            skv = fmaf(kvv, accV[i][j], skv);
            sks += kvv;
        }
        pKV[j]=skv; pKs[j]=sks;
    }
    __syncthreads();
    #pragma unroll
    for(int j=0;j<4;j++) red[cj+j][ti] = pKV[j];
    __syncthreads();
    if(t<64){
        float s2=0.f;
        for(int i=0;i<16;i++) s2 += red[t][i];
        atomicAdd(&ws[OFF_KV + b*256 + gh*64 + t], s2);
    }
    __syncthreads();
    #pragma unroll
    for(int j=0;j<4;j++) red[cj+j][ti] = pKs[j];
    __syncthreads();
    if(t<64){
        float s2=0.f;
        for(int i=0;i<16;i++) s2 += red[t][i];
        atomicAdd(&ws[OFF_KS + b*256 + gh*64 + t], s2);
    }
}

__global__ __launch_bounds__(256) void k_qo_f32(const float* __restrict__ x, const float* __restrict__ g,
                                            const float* __restrict__ wq, const float* __restrict__ wo,
                                            const float* __restrict__ ws, float* __restrict__ out){
    __shared__ float qT[512][32];
    __shared__ float sAT[16][32];
    __shared__ float sB[16][128];
    __shared__ float rl[32];
    __shared__ float KVl[256];
    __shared__ float Ksl[256];
    __shared__ float zb[256];
    const int t  = threadIdx.x;
    const int r0 = blockIdx.x * 32;
    const int b  = r0 / SEQ;
    if(t<32) rl[t] = ws[OFF_R + r0 + t];
    KVl[t] = ws[OFF_KV + b*256 + t];
    Ksl[t] = ws[OFF_KS + b*256 + t];
    const int ti = t & 7, tj = t >> 3;
    const int ri = ti*4, cj = tj*4;
    const int srow = t & 31, skk = (t>>5)*2;
    const int sj = t & 127, skkB = (t>>7)*8;
    const float* xrow = x + (size_t)(r0+srow)*DIM + skk;
    const float* gp = g + skk;
    __syncthreads();
    const float rr = rl[srow];
    for(int ct=0; ct<4; ct++){
        const float* wqb = wq + (size_t)(ct*128 + sj)*DIM + skkB;
        float acc[4][4];
        #pragma unroll
        for(int i=0;i<4;i++)
            #pragma unroll
            for(int j=0;j<4;j++) acc[i][j]=0.f;
        for(int k0=0;k0<DIM;k0+=16){
            float2 xa = *(const float2*)(xrow + k0);
            float2 ga = *(const float2*)(gp + k0);
            float4 wa = *(const float4*)(wqb + k0);
            float4 wb2= *(const float4*)(wqb + k0 + 4);
            __syncthreads();
            sAT[skk+0][srow] = xa.x*ga.x*rr;
            sAT[skk+1][srow] = xa.y*ga.y*rr;
            sB[skkB+0][sj]=wa.x; sB[skkB+1][sj]=wa.y; sB[skkB+2][sj]=wa.z; sB[skkB+3][sj]=wa.w;
            sB[skkB+4][sj]=wb2.x; sB[skkB+5][sj]=wb2.y; sB[skkB+6][sj]=wb2.z; sB[skkB+7][sj]=wb2.w;
            __syncthreads();
            #pragma unroll
            for(int kk=0;kk<16;kk++){
                float4 a = *(const float4*)&sAT[kk][ri];
                float4 bb= *(const float4*)&sB[kk][cj];
                float av[4]={a.x,a.y,a.z,a.w};
                float bv[4]={bb.x,bb.y,bb.z,bb.w};
                #pragma unroll
                for(int i=0;i<4;i++)
                    #pragma unroll
                    for(int j=0;j<4;j++)
                        acc[i][j] = fmaf(av[i], bv[j], acc[i][j]);
            }
        }
        #pragma unroll
        for(int i=0;i<4;i++)
            #pragma unroll
            for(int j=0;j<4;j++)
                qT[ct*128+cj+j][ri+i] = phi_f(acc[i][j]*SCALE);
    }
    __syncthreads();
    {
        const int row = t>>3, h = t&7;
        const float* ks = &Ksl[(h>>1)*64];
        float z = 0.f;
        #pragma unroll
        for(int d=0;d<64;d++) z = fmaf(qT[h*64+d][row], ks[d], z);
        zb[row*8+h] = 1.0f/(z + 1e-6f);
    }
    __syncthreads();
    #pragma unroll 4
    for(int i2=0;i2<64;i2++){
        int f = i2*256 + t;
        int col = f>>5, row = f&31;
        int h = col>>6;
        float kvv = KVl[((h>>1)<<6) + (col&63)];
        qT[col][row] *= kvv * zb[row*8+h];
    }
    __syncthreads();
    for(int ct=0;ct<4;ct++){
        const float* wob = wo + (size_t)(ct*128 + sj)*DIM + skkB;
        float acc[4][4];
        #pragma unroll
        for(int i=0;i<4;i++)
            #pragma unroll
            for(int j=0;j<4;j++) acc[i][j]=0.f;
        for(int k0=0;k0<DIM;k0+=16){
            float4 wa = *(const float4*)(wob + k0);
            float4 wb2= *(const float4*)(wob + k0 + 4);
            __syncthreads();
            sB[skkB+0][sj]=wa.x; sB[skkB+1][sj]=wa.y; sB[skkB+2][sj]=wa.z; sB[skkB+3][sj]=wa.w;
            sB[skkB+4][sj]=wb2.x; sB[skkB+5][sj]=wb2.y; sB[skkB+6][sj]=wb2.z; sB[skkB+7][sj]=wb2.w;
            __syncthreads();
            #pragma unroll
            for(int kk=0;kk<16;kk++){
                float4 a = *(const float4*)&qT[k0+kk][ri];
                float4 bb= *(const float4*)&sB[kk][cj];
                float av[4]={a.x,a.y,a.z,a.w};
                float bv[4]={bb.x,bb.y,bb.z,bb.w};
                #pragma unroll
                for(int i=0;i<4;i++)
                    #pragma unroll
                    for(int j=0;j<4;j++)
                        acc[i][j] = fmaf(av[i], bv[j], acc[i][j]);
            }
        }
        #pragma unroll
        for(int i=0;i<4;i++){
            float4 st; st.x=acc[i][0]; st.y=acc[i][1]; st.z=acc[i][2]; st.w=acc[i][3];
            *(float4*)(out + (size_t)(r0+ri+i)*DIM + ct*128 + cj) = st;
        }
    }
}

extern "C" void kernel_launch(void* const* d_in, const int* in_sizes, int n_in,
                              void* d_out, int out_size, void* d_ws, size_t ws_size,
                              hipStream_t stream){
    (void)in_sizes; (void)n_in; (void)out_size;
    const float* x  = (const float*)d_in[0];
    const float* g  = (const float*)d_in[1];
    const float* wq = (const float*)d_in[2];
    const float* wk = (const float*)d_in[3];
    const float* wv = (const float*)d_in[4];
    const float* wo = (const float*)d_in[5];
    float* out = (float*)d_out;

    if(ws_size >= WS_NEED){
        float* wsf = (float*)d_ws;
        ushort_t* wqb  = (ushort_t*)((char*)d_ws + 8192);
        ushort_t* wob  = wqb  + 262144;
        ushort_t* wkvb = wob  + 262144;
        ushort_t* hb   = wkvb + 262144;
        ushort_t* yb   = hb   + 16777216;

        hipLaunchKernelGGL(k_rmsh,    dim3(RTOT/4),      dim3(256), 0, stream, x, g, wsf, hb);
        hipLaunchKernelGGL(k_wcast,   dim3(768),         dim3(256), 0, stream, wq, wk, wv, wo, wqb, wob, wkvb);
        hipLaunchKernelGGL(k_kv_mfma, dim3(RTOT/128, 4), dim3(256), 0, stream, hb, wkvb, wsf);
        hipLaunchKernelGGL(k_q_mfma,  dim3(RTOT/128, 4), dim3(256), 0, stream, hb, wqb, wsf, yb);
        hipLaunchKernelGGL(k_out_mfma,dim3(RTOT/128, 4), dim3(256), 0, stream, yb, wob, out);
    } else {
        float* ws = (float*)d_ws;
        hipLaunchKernelGGL(k_rms_f32, dim3(RTOT/4),      dim3(256), 0, stream, x, ws);
        hipLaunchKernelGGL(k_kv_f32,  dim3(RTOT/128, 4), dim3(256), 0, stream, x, g, wk, wv, ws);
        hipLaunchKernelGGL(k_qo_f32,  dim3(RTOT/32),     dim3(256), 0, stream, x, g, wq, wo, ws, out);
    }
}